// Round 10
// baseline (366.554 us; speedup 1.0000x reference)
//
#include <hip/hip_runtime.h>
#include <math.h>

#define N 4096
#define D 2048
#define H 512
#define C 200
#define NR 8192  // 2N
#define LDH 40   // padded LDS row stride in halves (80 B) — k5

typedef unsigned long long u64;
typedef unsigned int u32;
typedef float f32x4 __attribute__((ext_vector_type(4)));
typedef float f32x16 __attribute__((ext_vector_type(16)));
typedef _Float16 f16x8 __attribute__((ext_vector_type(8)));
typedef _Float16 f16x4 __attribute__((ext_vector_type(4)));

__device__ __forceinline__ float sigm(float z) {
  return __builtin_amdgcn_rcpf(1.0f + __expf(-z));
}
__device__ __forceinline__ float bf2f(unsigned short u) { return __uint_as_float(((u32)u) << 16); }
__device__ __forceinline__ unsigned short f2bf(float x) {
  u32 u = __float_as_uint(x);
  return (unsigned short)((u + 0x7fffu + ((u >> 16) & 1u)) >> 16);  // RNE
}

// DMA global->LDS, 16 B per lane; LDS dest = uniform base + lane*16
__device__ __forceinline__ void gll16(const _Float16* g, _Float16* l) {
  __builtin_amdgcn_global_load_lds(
      (const __attribute__((address_space(1))) u32*)g,
      (__attribute__((address_space(3))) u32*)l, 16, 0, 0);
}

// ---------------- KC+K1 fused: pack feats into f16 hi/lo K32 panels + sumsq ----
// Panel layout: [ib(32)][kb(64)][row(128)][slot'(4)][8] halfs, slot' = slot^((row>>1)&3)
__global__ __launch_bounds__(256) void kc_pack_k1(const float* __restrict__ f,
                                                  _Float16* __restrict__ hiP,
                                                  _Float16* __restrict__ loP,
                                                  float* __restrict__ sq,
                                                  u64* __restrict__ bi,
                                                  u64* __restrict__ be) {
  __shared__ float wsum[4];
  const int r = blockIdx.x;
  const int t = threadIdx.x;
  const int kb = t >> 2, slot = t & 3;
  const float* src = f + (size_t)r * D + t * 8;
  float4 v0 = *(const float4*)src;
  float4 v1 = *(const float4*)(src + 4);
  f16x8 hv, lv;
  const float xs[8] = {v0.x, v0.y, v0.z, v0.w, v1.x, v1.y, v1.z, v1.w};
  float s = 0.0f;
#pragma unroll
  for (int j = 0; j < 8; ++j) {
    const _Float16 h = (_Float16)xs[j];
    hv[j] = h;
    lv[j] = (_Float16)(xs[j] - (float)h);
    s += xs[j] * xs[j];
  }
  const size_t off = ((size_t)((r >> 7) * 64 + kb) * 128 + (r & 127)) * 32 +
                     ((slot ^ ((r >> 1) & 3)) << 3);
  *(f16x8*)(hiP + off) = hv;
  *(f16x8*)(loP + off) = lv;
  for (int o = 32; o > 0; o >>= 1) s += __shfl_down(s, o);
  if ((t & 63) == 0) wsum[t >> 6] = s;
  __syncthreads();
  if (t == 0) {
    sq[r] = wsum[0] + wsum[1] + wsum[2] + wsum[3];
    bi[r] = ~0ull; be[r] = ~0ull;
  }
}

// ---------------- KC: transpose fp32 [R][Cc] -> f16 [Cc][R] (w2 only) ----------
__global__ void kc_T(const float* __restrict__ in, _Float16* __restrict__ out,
                     int R, int Cc) {
  __shared__ float t[32][33];
  const int c0 = blockIdx.x * 32, r0 = blockIdx.y * 32;
  for (int i = threadIdx.y; i < 32; i += 8)
    t[i][threadIdx.x] = in[(size_t)(r0 + i) * Cc + c0 + threadIdx.x];
  __syncthreads();
  for (int i = threadIdx.y; i < 32; i += 8)
    out[(size_t)(c0 + i) * R + r0 + threadIdx.x] = (_Float16)t[threadIdx.x][i];
}

// ---------------- KC: pack weight [K][Ncols] fp32 -> f16 K32 panels ------------
__global__ __launch_bounds__(256) void kc_packW(const float* __restrict__ w,
                                                _Float16* __restrict__ wP,
                                                int Ncols, int KB) {
  __shared__ float t[32][132];
  const int tid = threadIdx.x;
  const int kb = blockIdx.x, nb = blockIdx.y;
#pragma unroll
  for (int it = 0; it < 4; ++it) {
    const int idx = it * 256 + tid;  // 1024 float4 loads
    const int k = idx >> 5, nq = idx & 31;
    float4 v = *(const float4*)(w + (size_t)(kb * 32 + k) * Ncols + nb * 128 + nq * 4);
    t[k][nq * 4 + 0] = v.x; t[k][nq * 4 + 1] = v.y;
    t[k][nq * 4 + 2] = v.z; t[k][nq * 4 + 3] = v.w;
  }
  __syncthreads();
#pragma unroll
  for (int it = 0; it < 2; ++it) {
    const int idx = it * 256 + tid;  // 512 uint4 stores
    const int n = idx >> 2, slot = idx & 3;
    f16x8 v;
#pragma unroll
    for (int j = 0; j < 8; ++j) v[j] = (_Float16)t[slot * 8 + j][n];
    *(f16x8*)(wP + ((size_t)(nb * KB + kb) * 128 + n) * 32 +
              ((slot ^ ((n >> 1) & 3)) << 3)) = v;
  }
}

// ---------------- KC: wfc -> per-lane MFMA B-fragment layout (f16) ----------
__global__ __launch_bounds__(64) void kc_wfc(const float* __restrict__ wfc,
                                             _Float16* __restrict__ wfcP) {
  const int kc = blockIdx.x, nf = blockIdx.y, l = threadIdx.x;
  const int n = nf * 16 + (l & 15);
  const int k = kc * 32 + (l >> 4) * 8;
  f16x8 v;
#pragma unroll
  for (int j = 0; j < 8; ++j)
    v[j] = (n < C) ? (_Float16)wfc[(size_t)(k + j) * C + n] : (_Float16)0.0f;
  *(f16x8*)(wfcP + ((size_t)(kc * 14 + nf) * 64 + l) * 8) = v;
}

// ---------------- K2: Gram via 32x32x16 f16x3 MFMA, DMA double-buffer ----------
// Per wave: 2x2 tiles of 32x32 (64x64 output quadrant). One barrier per K32 step;
// STAGE(k+1) issued before MFMA(k) so DMA latency hides under compute (m97/T3).
__global__ __launch_bounds__(256, 2) void k2_dist(
    const _Float16* __restrict__ fhiP, const _Float16* __restrict__ floP,
    const int* __restrict__ tgt, const float* __restrict__ sq,
    u64* __restrict__ bi, u64* __restrict__ be) {
  __shared__ __align__(16) _Float16 S[2][4][4096];  // [dbuf][Ah,Al,Bh,Bl][128*32]
  __shared__ float sqi[128], sqj[128];
  __shared__ int ti[128], tj[128];
  __shared__ u64 Li[2][128], Lj[2][128];

  const int tid = threadIdx.x;
  const int bid = blockIdx.x;
  const int b = (bid & 7) * 66 + (bid >> 3);  // XCD chunk swizzle (528 = 8*66)
  int bj = (int)((sqrtf(8.0f * (float)b + 1.0f) - 1.0f) * 0.5f);
  while ((bj + 1) * (bj + 2) / 2 <= b) ++bj;
  while (bj * (bj + 1) / 2 > b) --bj;
  const int bib = b - bj * (bj + 1) / 2;
  const int i0 = bib * 128, j0 = bj * 128;
  const bool diag = (i0 == j0);

  const int l = tid & 63;
  const int w = tid >> 6;
  const int wr = w >> 1, wc = w & 1;
  const int c32 = l & 31, hi = l >> 5;

  // wave w stages panel w: 0=Ah 1=Al 2=Bh 3=Bl (pre-swizzled global source)
  const _Float16* psrc = ((w & 1) ? floP : fhiP) +
                         ((size_t)((w < 2 ? bib : bj) * 64) * 4096) + l * 8;
#define STAGE(kk, d)                                              \
  do {                                                            \
    const _Float16* gsrc_ = psrc + (size_t)(kk)*4096;             \
    _Float16* ldst_ = &S[d][w][0];                                \
    _Pragma("unroll") for (int ii = 0; ii < 8; ++ii)              \
        gll16(gsrc_ + ii * 512, ldst_ + ii * 512);                \
  } while (0)

  STAGE(0, 0);
  if (tid < 128) { sqi[tid] = sq[i0 + tid]; ti[tid] = tgt[i0 + tid]; }
  else { const int t = tid - 128; sqj[t] = sq[j0 + t]; tj[t] = tgt[j0 + t]; }
  ((u64*)Li)[tid] = ~0ull;
  ((u64*)Lj)[tid] = ~0ull;
  __syncthreads();  // stage 0 drained (vmcnt 0 at barrier)

  f32x16 acc[2][2] = {};

  for (int k = 0; k < 64; ++k) {
    const int cur = k & 1;
    if (k < 63) STAGE(k + 1, cur ^ 1);  // in flight across this step's MFMA phase
#pragma unroll
    for (int k16 = 0; k16 < 2; ++k16) {
      f16x8 ah[2], al[2], bh[2], bl[2];
#pragma unroll
      for (int t = 0; t < 2; ++t) {
        const int arow = wr * 64 + t * 32 + c32;
        const int aoff = arow * 32 + ((((k16 << 1) | hi) ^ ((arow >> 1) & 3)) << 3);
        ah[t] = *(const f16x8*)&S[cur][0][aoff];
        al[t] = *(const f16x8*)&S[cur][1][aoff];
        const int brow = wc * 64 + t * 32 + c32;
        const int boff = brow * 32 + ((((k16 << 1) | hi) ^ ((brow >> 1) & 3)) << 3);
        bh[t] = *(const f16x8*)&S[cur][2][boff];
        bl[t] = *(const f16x8*)&S[cur][3][boff];
      }
#pragma unroll
      for (int tm = 0; tm < 2; ++tm)
#pragma unroll
        for (int tn = 0; tn < 2; ++tn) {
          acc[tm][tn] = __builtin_amdgcn_mfma_f32_32x32x16_f16(ah[tm], bh[tn], acc[tm][tn], 0, 0, 0);
          acc[tm][tn] = __builtin_amdgcn_mfma_f32_32x32x16_f16(ah[tm], bl[tn], acc[tm][tn], 0, 0, 0);
          acc[tm][tn] = __builtin_amdgcn_mfma_f32_32x32x16_f16(al[tm], bh[tn], acc[tm][tn], 0, 0, 0);
        }
    }
    __syncthreads();  // reads of S[cur] done; stage into S[cur^1] drained
  }
#undef STAGE

  // ---- epilogue: row-i argmin (C/D: col=lane&31, row=(reg&3)+8*(reg>>2)+4*hi) --
#pragma unroll
  for (int tm = 0; tm < 2; ++tm) {
#pragma unroll
    for (int reg = 0; reg < 16; ++reg) {
      const int row_l = wr * 64 + tm * 32 + (reg & 3) + 8 * (reg >> 2) + 4 * hi;
      const float si = sqi[row_l];
      const int ci = ti[row_l];
      u64 ks = ~0ull, kd = ~0ull;
#pragma unroll
      for (int tn = 0; tn < 2; ++tn) {
        const int col_l = wc * 64 + tn * 32 + c32;
        const float d2 = si + sqj[col_l] - 2.0f * acc[tm][tn][reg];
        const u64 key = ((u64)__float_as_uint(d2) << 32) | (u32)(j0 + col_l);
        if (ci == tj[col_l]) {
          if (i0 + row_l != j0 + col_l) ks = key < ks ? key : ks;
        } else {
          kd = key < kd ? key : kd;
        }
      }
#pragma unroll
      for (int off = 1; off < 32; off <<= 1) {  // reduce over 32 cols (same hi half)
        u64 o = __shfl_xor(ks, off); ks = o < ks ? o : ks;
        o = __shfl_xor(kd, off);     kd = o < kd ? o : kd;
      }
      if (c32 == 0) {
        if (ks != ~0ull) atomicMin(&Li[0][row_l], ks);
        if (kd != ~0ull) atomicMin(&Li[1][row_l], kd);
      }
    }
  }
  // ---- epilogue: col-j argmin (off-diagonal blocks only) ----
  if (!diag) {
#pragma unroll
    for (int tn = 0; tn < 2; ++tn) {
      const int col_l = wc * 64 + tn * 32 + c32;
      const float sj = sqj[col_l];
      const int cj = tj[col_l];
      u64 ks = ~0ull, kd = ~0ull;
#pragma unroll
      for (int tm = 0; tm < 2; ++tm)
#pragma unroll
        for (int reg = 0; reg < 16; ++reg) {
          const int row_l = wr * 64 + tm * 32 + (reg & 3) + 8 * (reg >> 2) + 4 * hi;
          const float d2 = sqi[row_l] + sj - 2.0f * acc[tm][tn][reg];
          const u64 key = ((u64)__float_as_uint(d2) << 32) | (u32)(i0 + row_l);
          if (ti[row_l] == cj) ks = key < ks ? key : ks;
          else                 kd = key < kd ? key : kd;
        }
      // combine hi halves (lane^32 holds same col, other 32 rows)
      u64 o = __shfl_xor(ks, 32); ks = o < ks ? o : ks;
      o = __shfl_xor(kd, 32);     kd = o < kd ? o : kd;
      if (hi == 0) {
        if (ks != ~0ull) atomicMin(&Lj[0][col_l], ks);
        if (kd != ~0ull) atomicMin(&Lj[1][col_l], kd);
      }
    }
  }
  __syncthreads();
  if (tid < 128) {
    u64 v = Li[0][tid]; if (v != ~0ull) atomicMin(&bi[i0 + tid], v);
    v = Li[1][tid];     if (v != ~0ull) atomicMin(&be[i0 + tid], v);
  } else if (!diag) {
    const int t = tid - 128;
    u64 v = Lj[0][t]; if (v != ~0ull) atomicMin(&bi[j0 + t], v);
    v = Lj[1][t];     if (v != ~0ull) atomicMin(&be[j0 + t], v);
  }
}

// ---------------- K3: extract pair indices + write label outputs ----------------
__global__ __launch_bounds__(256) void k3_prep(const int* __restrict__ tgt,
                                               const u64* __restrict__ bi,
                                               const u64* __restrict__ be,
                                               int* __restrict__ iy,
                                               float* __restrict__ lab1,
                                               float* __restrict__ lab2) {
  const int r = blockIdx.x * 256 + threadIdx.x;
  if (r >= NR) return;
  if (r < N) {
    iy[r] = (int)(bi[r] & 0xffffffffull);
    const float t = (float)tgt[r];
    lab1[r] = t; lab2[r] = t;
  } else {
    const int s = r - N;
    const int j = (int)(be[s] & 0xffffffffull);
    iy[r] = j;
    lab1[r] = (float)tgt[s];
    lab2[r] = (float)tgt[j];
  }
}

// ---------------- K4: h = [x,y] @ w1 + b1, 64x128 tile, DMA-staged -------------
__global__ __launch_bounds__(256, 4) void k4_h(const _Float16* __restrict__ fhiP,
                                               const _Float16* __restrict__ w1P,
                                               const float* __restrict__ b1,
                                               const int* __restrict__ iy,
                                               _Float16* __restrict__ hout) {
  __shared__ __align__(16) _Float16 As[2 * 2048];  // [p][row(64)][slot'][8]
  __shared__ __align__(16) _Float16 Bs[2 * 4096];  // [p][n(128)][slot'][8]
  __shared__ int iy_s[64];
  const int tid = threadIdx.x;
  const int bid = blockIdx.x;
  const int b = (bid & 7) * 64 + (bid >> 3);  // XCD chunk swizzle (512 = 8*64)
  const int nIdx = b >> 7, mIdx = b & 127;    // same-B blocks consecutive per XCD
  const int r0 = mIdx * 64, n0 = nIdx * 128;
  if (tid < 64) iy_s[tid] = iy[r0 + tid];
  const int l = tid & 63, w = tid >> 6;
  const int fr = l & 15, fg = l >> 4;
  const int pswz = ((fr >> 1) & 3) << 3;
  f32x4 acc[4][2] = {};
  const int gr0 = r0 & (N - 1);  // 64-aligned -> swizzle phase matches local rows
  const _Float16* paBase = fhiP + ((size_t)((gr0 >> 7) * 64) * 4096) + (gr0 & 127) * 32;

#define K4_MFMA()                                                                   \
  do {                                                                              \
    _Pragma("unroll") for (int p = 0; p < 2; ++p) {                                 \
      f16x8 a[4], bb[2];                                                            \
      _Pragma("unroll") for (int m = 0; m < 4; ++m)                                 \
        a[m] = *(const f16x8*)&As[p * 2048 + (m * 16 + fr) * 32 + ((fg << 3) ^ pswz)]; \
      _Pragma("unroll") for (int nf = 0; nf < 2; ++nf)                              \
        bb[nf] = *(const f16x8*)&Bs[p * 4096 + (w * 32 + nf * 16 + fr) * 32 +       \
                                    ((fg << 3) ^ pswz)];                            \
      _Pragma("unroll") for (int m = 0; m < 4; ++m)                                 \
        _Pragma("unroll") for (int nf = 0; nf < 2; ++nf)                            \
          acc[m][nf] = __builtin_amdgcn_mfma_f32_16x16x32_f16(a[m], bb[nf],         \
                                                              acc[m][nf], 0, 0, 0); \
    }                                                                               \
  } while (0)

  // ---- x-half: k in [0, D) ----
  for (int ks = 0; ks < 32; ++ks) {
    const int kbA = ks * 2;
    __syncthreads();
    {
      const _Float16* pa = paBase + (size_t)kbA * 4096 + l * 8;
      const _Float16* pb = w1P + (size_t)(nIdx * 128 + kbA) * 4096 + l * 8;
#pragma unroll
      for (int cc = 0; cc < 6; ++cc) {
        const int c = w * 6 + cc;  // 24 chunks of 1 KB: 0..7 A, 8..23 B
        if (c < 8) {
          const int p = c >> 2, co = c & 3;
          gll16(pa + p * 4096 + co * 512, &As[p * 2048 + co * 512]);
        } else {
          const int cb = c - 8;
          gll16(pb + cb * 512, &Bs[cb * 512]);
        }
      }
    }
    __syncthreads();
    K4_MFMA();
  }
  // ---- y-half: k in [D, 2D) ----
  for (int ks = 0; ks < 32; ++ks) {
    const int kbA = ks * 2;
    const int kbW = 64 + ks * 2;
    __syncthreads();
    {
      const _Float16* pb = w1P + (size_t)(nIdx * 128 + kbW) * 4096 + l * 8;
#pragma unroll
      for (int cc = 0; cc < 4; ++cc) {
        const int cb = w * 4 + cc;
        gll16(pb + cb * 512, &Bs[cb * 512]);
      }
    }
#pragma unroll
    for (int it = 0; it < 2; ++it) {
      const int idx = it * 256 + tid;
      const int row = idx >> 3, p = (idx >> 2) & 1, slot = idx & 3;
      const int gy = iy_s[row];
      const _Float16* src = fhiP +
          ((size_t)((gy >> 7) * 64 + kbA + p) * 128 + (gy & 127)) * 32 +
          ((slot ^ ((gy >> 1) & 3)) << 3);
      *(uint4*)&As[p * 2048 + row * 32 + ((slot ^ ((row >> 1) & 3)) << 3)] =
          *(const uint4*)src;
    }
    __syncthreads();
    K4_MFMA();
  }
#undef K4_MFMA

#pragma unroll
  for (int nf = 0; nf < 2; ++nf) {
    const int gcol = n0 + w * 32 + nf * 16 + fr;
    const float bias = b1[gcol];
#pragma unroll
    for (int m = 0; m < 4; ++m)
#pragma unroll
      for (int reg = 0; reg < 4; ++reg) {
        const int grow = r0 + m * 16 + fg * 4 + reg;
        hout[(size_t)grow * H + gcol] = (_Float16)(acc[m][nf][reg] + bias);
      }
  }
}

// ---------------- K5: m = h @ w2 + b2 via f16 MFMA (bf16 out) ----------------
__global__ __launch_bounds__(256, 4) void k5_m(const _Float16* __restrict__ hbuf,
                                               const _Float16* __restrict__ w2T,
                                               const float* __restrict__ b2,
                                               unsigned short* __restrict__ mbuf) {
  __shared__ __align__(16) _Float16 As[128 * LDH], Bs[128 * LDH];
  const int tid = threadIdx.x;
  const int bid = blockIdx.x;
  const int b = (bid & 7) * 128 + (bid >> 3);  // XCD chunk swizzle (1024 = 8*128)
  const int n0 = (b & 15) * 128, r0 = (b >> 4) * 128;
  const int l = tid & 63, w = tid >> 6;
  const int wr = w >> 1, wc = w & 1, fr = l & 15, fg = l >> 4;
  f32x4 acc[4][4] = {};

  for (int k0 = 0; k0 < H; k0 += 32) {
    __syncthreads();
#pragma unroll
    for (int it = 0; it < 2; ++it) {
      const int c = it * 256 + tid;
      const int row = c >> 2, xc = c & 3;
      const int la = row * LDH + xc * 8;
      *(uint4*)&As[la] = *(const uint4*)(hbuf + (size_t)(r0 + row) * H + k0 + xc * 8);
      *(uint4*)&Bs[la] = *(const uint4*)(w2T + (size_t)(n0 + row) * H + k0 + xc * 8);
    }
    __syncthreads();
    f16x8 a[4], bb[4];
#pragma unroll
    for (int m = 0; m < 4; ++m) a[m] = *(const f16x8*)&As[(wr * 64 + m * 16 + fr) * LDH + fg * 8];
#pragma unroll
    for (int n = 0; n < 4; ++n) bb[n] = *(const f16x8*)&Bs[(wc * 64 + n * 16 + fr) * LDH + fg * 8];
#pragma unroll
    for (int m = 0; m < 4; ++m)
#pragma unroll
      for (int n = 0; n < 4; ++n)
        acc[m][n] = __builtin_amdgcn_mfma_f32_16x16x32_f16(a[m], bb[n], acc[m][n], 0, 0, 0);
  }
#pragma unroll
  for (int n = 0; n < 4; ++n) {
    const int gcol = n0 + wc * 64 + n * 16 + fr;
    const float bias = b2[gcol];
#pragma unroll
    for (int m = 0; m < 4; ++m)
#pragma unroll
      for (int reg = 0; reg < 4; ++reg) {
        const int grow = r0 + wr * 64 + m * 16 + fg * 4 + reg;
        mbuf[(size_t)grow * D + gcol] = f2bf(acc[m][n][reg] + bias);
      }
  }
}

// ---------------- K6: fused gates + 4 logit GEMMs, dbuf DMA-B, gate/MFMA overlap
__global__ __launch_bounds__(256, 2) void k6_logits(
    const float* __restrict__ feats, const unsigned short* __restrict__ mbuf,
    const int* __restrict__ iy, const _Float16* __restrict__ wfcP,
    const float* __restrict__ bfc, float* __restrict__ out) {
  __shared__ __align__(16) _Float16 As[2][64 * 64];   // 16 KB: gated A, dbuf
  __shared__ __align__(16) _Float16 Bs[2][14336];     // 56 KB: wfcP chunk, dbuf
  __shared__ int iy_s[16];
  const int tid = threadIdx.x;
  const int r0 = blockIdx.x * 16;
  const int l = tid & 63, v = tid >> 6;  // wave = variant
  const int fr = l & 15, fg = l >> 4;
  if (tid < 16) iy_s[tid] = iy[r0 + tid];
  __syncthreads();
  const int rr = tid >> 4;           // base row 0..15
  const int kq = (tid & 15) << 2;    // k offset within K64 chunk
  const int rg = r0 + rr;
  const float* xptr = feats + (size_t)(rg & (N - 1)) * D;
  const float* yptr = feats + (size_t)iy_s[rr] * D;
  const unsigned short* mptr = mbuf + (size_t)rg * D;
  const int wsw = ((rr >> 1) & 3) | ((rr & 1) << 2);               // write perm (3-bit)
  const int soff = ((((kq >> 3) ^ wsw)) << 3) + (kq & 7);
  const int rsw = (((fr >> 1) & 3) | ((fr & 1) << 2)) << 3;        // read perm << 3

  f32x4 acc[14] = {};

#define K6_GATES(buf, xv, yv, mv)                                     \
  do {                                                                \
    const float xs_[4] = {xv.x, xv.y, xv.z, xv.w};                    \
    const float ys_[4] = {yv.x, yv.y, yv.z, yv.w};                    \
    const unsigned short ms_[4] = {mv.x, mv.y, mv.z, mv.w};           \
    f16x4 a0, a1, a2, a3;                                             \
    _Pragma("unroll") for (int j = 0; j < 4; ++j) {                   \
      const float x = xs_[j], y = ys_[j], m = bf2f(ms_[j]);           \
      const float gx = sigm(m * x), gy = sigm(m * y);                 \
      a0[j] = (_Float16)(x * (1.0f + gx));                            \
      a1[j] = (_Float16)(x * (1.0f + gy));                            \
      a2[j] = (_Float16)(y * (1.0f + gy));                            \
      a3[j] = (_Float16)(y * (1.0f + gx));                            \
    }                                                                 \
    *(f16x4*)&As[buf][(rr)*64 + soff] = a0;                           \
    *(f16x4*)&As[buf][(16 + rr) * 64 + soff] = a1;                    \
    *(f16x4*)&As[buf][(32 + rr) * 64 + soff] = a2;                    \
    *(f16x4*)&As[buf][(48 + rr) * 64 + soff] = a3;                    \
  } while (0)

#define K6_STAGEB(k0n, buf)                                           \
  do {                                                                \
    const _Float16* src_ = wfcP + (size_t)((k0n) >> 5) * 7168;        \
    _Pragma("unroll") for (int c = 0; c < 7; ++c)                     \
      gll16(src_ + (c * 256 + tid) * 8, &Bs[buf][(c * 256 + tid) * 8]); \
  } while (0)

  // prologue: chunk 0 gates + B stage
  {
    float4 xv = *(const float4*)(xptr + kq);
    float4 yv = *(const float4*)(yptr + kq);
    ushort4 mv = *(const ushort4*)(mptr + kq);
    K6_STAGEB(0, 0);
    K6_GATES(0, xv, yv, mv);
  }

  for (int k0 = 0; k0 < D; k0 += 64) {
    const int cur = (k0 >> 6) & 1;
    __syncthreads();  // As[cur]/Bs[cur] ready (DMA drained, gate writes visible)
    float4 xv, yv; ushort4 mv;
    const bool more = (k0 + 64 < D);
    if (more) {  // issue next chunk's loads + DMA now; hide under MFMA phase
      xv = *(const float4*)(xptr + k0 + 64 + kq);
      yv = *(const float4*)(yptr + k0 + 64 + kq);
      mv = *(const ushort4*)(mptr + k0 + 64 + kq);
      K6_STAGEB(k0 + 64, cur ^ 1);
    }
#pragma unroll
    for (int ksl = 0; ksl < 2; ++ksl) {
      const f16x8 af =
          *(const f16x8*)&As[cur][(v * 16 + fr) * 64 + ((((ksl * 4 + fg) << 3)) ^ rsw)];
      const _Float16* bp = &Bs[cur][(size_t)ksl * 7168 + (size_t)l * 8];
#pragma unroll
      for (int nf = 0; nf < 14; ++nf) {
        const f16x8 bf = *(const f16x8*)(bp + nf * 512);
        acc[nf] = __builtin_amdgcn_mfma_f32_16x16x32_f16(af, bf, acc[nf], 0, 0, 0);
      }
    }
    if (more) K6_GATES(cur ^ 1, xv, yv, mv);  // VALU overlaps MFMA pipe
  }
#undef K6_GATES
#undef K6_STAGEB

  float* outv = out + (size_t)v * NR * C;
#pragma unroll
  for (int nf = 0; nf < 14; ++nf) {
    const int col = nf * 16 + fr;
    if (col < C) {
      const float bias = bfc[col];
#pragma unroll
      for (int reg = 0; reg < 4; ++reg) {
        const int row = r0 + fg * 4 + reg;
        outv[(size_t)row * C + col] = sigm(acc[nf][reg] + bias);
      }
    }
  }
}

extern "C" void kernel_launch(void* const* d_in, const int* in_sizes, int n_in,
                              void* d_out, int out_size, void* d_ws, size_t ws_size,
                              hipStream_t stream) {
  const float* feats = (const float*)d_in[0];
  const int*   tgt   = (const int*)d_in[1];
  const float* w1    = (const float*)d_in[2];
  const float* b1    = (const float*)d_in[3];
  const float* w2    = (const float*)d_in[4];
  const float* b2    = (const float*)d_in[5];
  const float* wfc   = (const float*)d_in[6];
  const float* bfc   = (const float*)d_in[7];
  float* out = (float*)d_out;

  char* ws = (char*)d_ws;
  float* sq = (float*)(ws);                       // 16 KB
  u64*   bi = (u64*)(ws + 16384);                 // 32 KB
  u64*   be = (u64*)(ws + 49152);                 // 32 KB
  int*   iy = (int*)(ws + 81920);                 // 32 KB
  _Float16* fhiP = (_Float16*)(ws + 131072);                 // 16 MB packed
  _Float16* floP = (_Float16*)(ws + 131072 + 16777216);      // 16 MB packed
  // mbuf (32 MB bf16) aliases fhiP+floP — both dead after k4 (k5 writes, k6 reads)
  unsigned short* mbuf = (unsigned short*)(ws + 131072);
  _Float16* w1P = (_Float16*)(ws + 33685504);                // 4 MB packed panels
  _Float16* w2T = (_Float16*)(ws + 37879808);                // 2 MB
  _Float16* hbuf = (_Float16*)(ws + 39976960);               // 8 MB
  _Float16* wfcP = (_Float16*)(ws + 48365568);               // 0.9 MB

  float* lab1 = out + (size_t)4 * NR * C;
  float* lab2 = lab1 + NR;

  kc_pack_k1<<<N, 256, 0, stream>>>(feats, fhiP, floP, sq, bi, be);
  kc_packW<<<dim3(128, 4), 256, 0, stream>>>(w1, w1P, 512, 128);
  kc_T<<<dim3(2048 / 32, 512 / 32), dim3(32, 8), 0, stream>>>(w2, w2T, 512, 2048);
  kc_wfc<<<dim3(64, 14), 64, 0, stream>>>(wfc, wfcP);
  k2_dist<<<528, 256, 0, stream>>>(fhiP, floP, tgt, sq, bi, be);
  k3_prep<<<NR / 256, 256, 0, stream>>>(tgt, bi, be, iy, lab1, lab2);
  k4_h<<<512, 256, 0, stream>>>(fhiP, w1P, b1, iy, hbuf);
  k5_m<<<1024, 256, 0, stream>>>(hbuf, w2T, b2, mbuf);
  k6_logits<<<NR / 16, 256, 0, stream>>>(feats, mbuf, iy, wfcP, bfc, out);
}

// Round 11
// 294.781 us; speedup vs baseline: 1.2435x; 1.2435x over previous
//
#include <hip/hip_runtime.h>
#include <math.h>

#define N 4096
#define D 2048
#define H 512
#define C 200
#define NR 8192  // 2N
#define LDH 40   // padded LDS row stride in halves (80 B) — k5

typedef unsigned long long u64;
typedef unsigned int u32;
typedef float f32x4 __attribute__((ext_vector_type(4)));
typedef _Float16 f16x8 __attribute__((ext_vector_type(8)));
typedef _Float16 f16x4 __attribute__((ext_vector_type(4)));

__device__ __forceinline__ float sigm(float z) {
  // v_exp_f32-based fast sigmoid; rel err ~1e-6 (vs 0.0039 tolerance margin)
  return __builtin_amdgcn_rcpf(1.0f + __expf(-z));
}
__device__ __forceinline__ float bf2f(unsigned short u) { return __uint_as_float(((u32)u) << 16); }
__device__ __forceinline__ unsigned short f2bf(float x) {
  u32 u = __float_as_uint(x);
  return (unsigned short)((u + 0x7fffu + ((u >> 16) & 1u)) >> 16);  // RNE
}

// DMA global->LDS, 16 B per lane; LDS dest = uniform base + lane*16
__device__ __forceinline__ void gll16(const _Float16* g, _Float16* l) {
  __builtin_amdgcn_global_load_lds(
      (const __attribute__((address_space(1))) u32*)g,
      (__attribute__((address_space(3))) u32*)l, 16, 0, 0);
}

// ---------------- KC+K1 fused: pack feats into f16 hi/lo K32 panels + sumsq ----
// Panel layout: [ib(32)][kb(64)][row(128)][slot'(4)][8] halfs, slot' = slot^((row>>1)&3)
__global__ __launch_bounds__(256) void kc_pack_k1(const float* __restrict__ f,
                                                  _Float16* __restrict__ hiP,
                                                  _Float16* __restrict__ loP,
                                                  float* __restrict__ sq,
                                                  u64* __restrict__ bi,
                                                  u64* __restrict__ be) {
  __shared__ float wsum[4];
  const int r = blockIdx.x;
  const int t = threadIdx.x;
  const int kb = t >> 2, slot = t & 3;
  const float* src = f + (size_t)r * D + t * 8;
  float4 v0 = *(const float4*)src;
  float4 v1 = *(const float4*)(src + 4);
  f16x8 hv, lv;
  const float xs[8] = {v0.x, v0.y, v0.z, v0.w, v1.x, v1.y, v1.z, v1.w};
  float s = 0.0f;
#pragma unroll
  for (int j = 0; j < 8; ++j) {
    const _Float16 h = (_Float16)xs[j];
    hv[j] = h;
    lv[j] = (_Float16)(xs[j] - (float)h);
    s += xs[j] * xs[j];
  }
  const size_t off = ((size_t)((r >> 7) * 64 + kb) * 128 + (r & 127)) * 32 +
                     ((slot ^ ((r >> 1) & 3)) << 3);
  *(f16x8*)(hiP + off) = hv;
  *(f16x8*)(loP + off) = lv;
  for (int o = 32; o > 0; o >>= 1) s += __shfl_down(s, o);
  if ((t & 63) == 0) wsum[t >> 6] = s;
  __syncthreads();
  if (t == 0) {
    sq[r] = wsum[0] + wsum[1] + wsum[2] + wsum[3];
    bi[r] = ~0ull; be[r] = ~0ull;
  }
}

// ---------------- KC: transpose fp32 [R][Cc] -> f16 [Cc][R] (w2 only) ----------
__global__ void kc_T(const float* __restrict__ in, _Float16* __restrict__ out,
                     int R, int Cc) {
  __shared__ float t[32][33];
  const int c0 = blockIdx.x * 32, r0 = blockIdx.y * 32;
  for (int i = threadIdx.y; i < 32; i += 8)
    t[i][threadIdx.x] = in[(size_t)(r0 + i) * Cc + c0 + threadIdx.x];
  __syncthreads();
  for (int i = threadIdx.y; i < 32; i += 8)
    out[(size_t)(c0 + i) * R + r0 + threadIdx.x] = (_Float16)t[threadIdx.x][i];
}

// ---------------- KC: pack weight [K][Ncols] fp32 -> f16 K32 panels ------------
// wP[nb][kb][n(128)][slot'][8], slot' = slot ^ ((n>>1)&3)
__global__ __launch_bounds__(256) void kc_packW(const float* __restrict__ w,
                                                _Float16* __restrict__ wP,
                                                int Ncols, int KB) {
  __shared__ float t[32][132];
  const int tid = threadIdx.x;
  const int kb = blockIdx.x, nb = blockIdx.y;
#pragma unroll
  for (int it = 0; it < 4; ++it) {
    const int idx = it * 256 + tid;  // 1024 float4 loads
    const int k = idx >> 5, nq = idx & 31;
    float4 v = *(const float4*)(w + (size_t)(kb * 32 + k) * Ncols + nb * 128 + nq * 4);
    t[k][nq * 4 + 0] = v.x; t[k][nq * 4 + 1] = v.y;
    t[k][nq * 4 + 2] = v.z; t[k][nq * 4 + 3] = v.w;
  }
  __syncthreads();
#pragma unroll
  for (int it = 0; it < 2; ++it) {
    const int idx = it * 256 + tid;  // 512 uint4 stores
    const int n = idx >> 2, slot = idx & 3;
    f16x8 v;
#pragma unroll
    for (int j = 0; j < 8; ++j) v[j] = (_Float16)t[slot * 8 + j][n];
    *(f16x8*)(wP + ((size_t)(nb * KB + kb) * 128 + n) * 32 +
              ((slot ^ ((n >> 1) & 3)) << 3)) = v;
  }
}

// ---------------- KC: wfc -> per-lane MFMA B-fragment layout (f16) ----------
__global__ __launch_bounds__(64) void kc_wfc(const float* __restrict__ wfc,
                                             _Float16* __restrict__ wfcP) {
  const int kc = blockIdx.x, nf = blockIdx.y, l = threadIdx.x;
  const int n = nf * 16 + (l & 15);
  const int k = kc * 32 + (l >> 4) * 8;
  f16x8 v;
#pragma unroll
  for (int j = 0; j < 8; ++j)
    v[j] = (n < C) ? (_Float16)wfc[(size_t)(k + j) * C + n] : (_Float16)0.0f;
  *(f16x8*)(wfcP + ((size_t)(kc * 14 + nf) * 64 + l) * 8) = v;
}

// ---------------- K2: Gram via f16x3 MFMA, DMA single-buffer, triangle+argmin --
// Measured best (R8): 127 us, 837 TF eff, 0 bank conflicts, MfmaUtil 36.5% =
// 93% of the 128^2/2-barrier structure ceiling (m97 ladder). Dbuf-over-barrier
// (R10) and 32x32 tiles (R10) and launch_bounds 4 (R9) all failed to beat it.
__global__ __launch_bounds__(256, 2) void k2_dist(
    const _Float16* __restrict__ fhiP, const _Float16* __restrict__ floP,
    const int* __restrict__ tgt, const float* __restrict__ sq,
    u64* __restrict__ bi, u64* __restrict__ be) {
  __shared__ __align__(16) _Float16 S[4][4096];  // Ah, Al, Bh, Bl panels (8 KB ea)
  __shared__ float sqi[128], sqj[128];
  __shared__ int ti[128], tj[128];
  __shared__ u64 Li[2][128], Lj[2][128];

  const int tid = threadIdx.x;
  const int bid = blockIdx.x;
  const int b = (bid & 7) * 66 + (bid >> 3);  // XCD chunk swizzle (528 = 8*66)
  int bj = (int)((sqrtf(8.0f * (float)b + 1.0f) - 1.0f) * 0.5f);
  while ((bj + 1) * (bj + 2) / 2 <= b) ++bj;
  while (bj * (bj + 1) / 2 > b) --bj;
  const int bib = b - bj * (bj + 1) / 2;
  const int i0 = bib * 128, j0 = bj * 128;
  const bool diag = (i0 == j0);

  const int l = tid & 63;
  const int w = tid >> 6;
  const int wr = w >> 1, wc = w & 1;
  const int fr = l & 15, fg = l >> 4;
  const int pswz = ((fr >> 1) & 3) << 3;  // read-slot swizzle (x8 halfs)

  // wave w stages panel w: 0=Ah 1=Al 2=Bh 3=Bl (pre-swizzled global source)
  const _Float16* psrc = ((w & 1) ? floP : fhiP) +
                         ((size_t)((w < 2 ? bib : bj) * 64) * 4096) + l * 8;

  if (tid < 128) { sqi[tid] = sq[i0 + tid]; ti[tid] = tgt[i0 + tid]; }
  else { const int t = tid - 128; sqj[t] = sq[j0 + t]; tj[t] = tgt[j0 + t]; }
  ((u64*)Li)[tid] = ~0ull;
  ((u64*)Lj)[tid] = ~0ull;

  f32x4 acc[4][4] = {};

  for (int k = 0; k < 64; ++k) {
    {  // stage this K-step's 32 KB via DMA (no VGPR round-trip)
      const _Float16* gsrc = psrc + (size_t)k * 4096;
      _Float16* ldst = &S[w][0];
#pragma unroll
      for (int ii = 0; ii < 8; ++ii) gll16(gsrc + ii * 512, ldst + ii * 512);
    }
    __syncthreads();  // drains vmcnt(0): DMA landed, visible to all waves
    f16x8 ah[4], al[4], bh[4], bl[4];
#pragma unroll
    for (int m = 0; m < 4; ++m) {
      const int off = (wr * 64 + m * 16 + fr) * 32 + ((fg << 3) ^ pswz);
      ah[m] = *(const f16x8*)&S[0][off];
      al[m] = *(const f16x8*)&S[1][off];
    }
#pragma unroll
    for (int n = 0; n < 4; ++n) {
      const int off = (wc * 64 + n * 16 + fr) * 32 + ((fg << 3) ^ pswz);
      bh[n] = *(const f16x8*)&S[2][off];
      bl[n] = *(const f16x8*)&S[3][off];
    }
#pragma unroll
    for (int m = 0; m < 4; ++m)
#pragma unroll
      for (int n = 0; n < 4; ++n) {
        acc[m][n] = __builtin_amdgcn_mfma_f32_16x16x32_f16(ah[m], bh[n], acc[m][n], 0, 0, 0);
        acc[m][n] = __builtin_amdgcn_mfma_f32_16x16x32_f16(ah[m], bl[n], acc[m][n], 0, 0, 0);
        acc[m][n] = __builtin_amdgcn_mfma_f32_16x16x32_f16(al[m], bh[n], acc[m][n], 0, 0, 0);
      }
    __syncthreads();  // all reads done before next stage overwrites
  }

  // ---- epilogue: row-i argmin ----
#pragma unroll
  for (int m = 0; m < 4; ++m) {
#pragma unroll
    for (int reg = 0; reg < 4; ++reg) {
      const int row_l = wr * 64 + m * 16 + fg * 4 + reg;
      const float si = sqi[row_l];
      const int ci = ti[row_l];
      u64 ks = ~0ull, kd = ~0ull;
#pragma unroll
      for (int n = 0; n < 4; ++n) {
        const int col_l = wc * 64 + n * 16 + fr;
        const float d2 = si + sqj[col_l] - 2.0f * acc[m][n][reg];
        const u64 key = ((u64)__float_as_uint(d2) << 32) | (u32)(j0 + col_l);
        if (ci == tj[col_l]) {
          if (i0 + row_l != j0 + col_l) ks = key < ks ? key : ks;
        } else {
          kd = key < kd ? key : kd;
        }
      }
#pragma unroll
      for (int off = 1; off < 16; off <<= 1) {
        u64 o = __shfl_xor(ks, off); ks = o < ks ? o : ks;
        o = __shfl_xor(kd, off);     kd = o < kd ? o : kd;
      }
      if (fr == 0) {
        if (ks != ~0ull) atomicMin(&Li[0][row_l], ks);
        if (kd != ~0ull) atomicMin(&Li[1][row_l], kd);
      }
    }
  }
  // ---- epilogue: col-j argmin (off-diagonal blocks only) ----
  if (!diag) {
#pragma unroll
    for (int n = 0; n < 4; ++n) {
      const int col_l = wc * 64 + n * 16 + fr;
      const float sj = sqj[col_l];
      const int cj = tj[col_l];
      u64 ks = ~0ull, kd = ~0ull;
#pragma unroll
      for (int m = 0; m < 4; ++m)
#pragma unroll
        for (int reg = 0; reg < 4; ++reg) {
          const int row_l = wr * 64 + m * 16 + fg * 4 + reg;
          const float d2 = sqi[row_l] + sj - 2.0f * acc[m][n][reg];
          const u64 key = ((u64)__float_as_uint(d2) << 32) | (u32)(i0 + row_l);
          if (ti[row_l] == cj) ks = key < ks ? key : ks;
          else                 kd = key < kd ? key : kd;
        }
#pragma unroll
      for (int off = 16; off < 64; off <<= 1) {
        u64 o = __shfl_xor(ks, off); ks = o < ks ? o : ks;
        o = __shfl_xor(kd, off);     kd = o < kd ? o : kd;
      }
      if (fg == 0) {
        if (ks != ~0ull) atomicMin(&Lj[0][col_l], ks);
        if (kd != ~0ull) atomicMin(&Lj[1][col_l], kd);
      }
    }
  }
  __syncthreads();
  if (tid < 128) {
    u64 v = Li[0][tid]; if (v != ~0ull) atomicMin(&bi[i0 + tid], v);
    v = Li[1][tid];     if (v != ~0ull) atomicMin(&be[i0 + tid], v);
  } else if (!diag) {
    const int t = tid - 128;
    u64 v = Lj[0][t]; if (v != ~0ull) atomicMin(&bi[j0 + t], v);
    v = Lj[1][t];     if (v != ~0ull) atomicMin(&be[j0 + t], v);
  }
}

// ---------------- K3: extract pair indices + write label outputs ----------------
__global__ __launch_bounds__(256) void k3_prep(const int* __restrict__ tgt,
                                               const u64* __restrict__ bi,
                                               const u64* __restrict__ be,
                                               int* __restrict__ iy,
                                               float* __restrict__ lab1,
                                               float* __restrict__ lab2) {
  const int r = blockIdx.x * 256 + threadIdx.x;
  if (r >= NR) return;
  if (r < N) {
    iy[r] = (int)(bi[r] & 0xffffffffull);
    const float t = (float)tgt[r];
    lab1[r] = t; lab2[r] = t;
  } else {
    const int s = r - N;
    const int j = (int)(be[s] & 0xffffffffull);
    iy[r] = j;
    lab1[r] = (float)tgt[s];
    lab2[r] = (float)tgt[j];
  }
}

// ---------------- K4: h = [x,y] @ w1 + b1, 64x128 tile, DMA-staged -------------
__global__ __launch_bounds__(256, 4) void k4_h(const _Float16* __restrict__ fhiP,
                                               const _Float16* __restrict__ w1P,
                                               const float* __restrict__ b1,
                                               const int* __restrict__ iy,
                                               _Float16* __restrict__ hout) {
  __shared__ __align__(16) _Float16 As[2 * 2048];  // [p][row(64)][slot'][8]
  __shared__ __align__(16) _Float16 Bs[2 * 4096];  // [p][n(128)][slot'][8]
  __shared__ int iy_s[64];
  const int tid = threadIdx.x;
  const int bid = blockIdx.x;
  const int b = (bid & 7) * 64 + (bid >> 3);  // XCD chunk swizzle (512 = 8*64)
  const int nIdx = b >> 7, mIdx = b & 127;    // same-B blocks consecutive per XCD
  const int r0 = mIdx * 64, n0 = nIdx * 128;
  if (tid < 64) iy_s[tid] = iy[r0 + tid];
  const int l = tid & 63, w = tid >> 6;
  const int fr = l & 15, fg = l >> 4;
  const int pswz = ((fr >> 1) & 3) << 3;
  f32x4 acc[4][2] = {};
  const int gr0 = r0 & (N - 1);  // 64-aligned -> swizzle phase matches local rows
  const _Float16* paBase = fhiP + ((size_t)((gr0 >> 7) * 64) * 4096) + (gr0 & 127) * 32;

#define K4_MFMA()                                                                   \
  do {                                                                              \
    _Pragma("unroll") for (int p = 0; p < 2; ++p) {                                 \
      f16x8 a[4], bb[2];                                                            \
      _Pragma("unroll") for (int m = 0; m < 4; ++m)                                 \
        a[m] = *(const f16x8*)&As[p * 2048 + (m * 16 + fr) * 32 + ((fg << 3) ^ pswz)]; \
      _Pragma("unroll") for (int nf = 0; nf < 2; ++nf)                              \
        bb[nf] = *(const f16x8*)&Bs[p * 4096 + (w * 32 + nf * 16 + fr) * 32 +       \
                                    ((fg << 3) ^ pswz)];                            \
      _Pragma("unroll") for (int m = 0; m < 4; ++m)                                 \
        _Pragma("unroll") for (int nf = 0; nf < 2; ++nf)                            \
          acc[m][nf] = __builtin_amdgcn_mfma_f32_16x16x32_f16(a[m], bb[nf],         \
                                                              acc[m][nf], 0, 0, 0); \
    }                                                                               \
  } while (0)

  // ---- x-half: k in [0, D) ----
  for (int ks = 0; ks < 32; ++ks) {
    const int kbA = ks * 2;
    __syncthreads();
    {
      const _Float16* pa = paBase + (size_t)kbA * 4096 + l * 8;
      const _Float16* pb = w1P + (size_t)(nIdx * 128 + kbA) * 4096 + l * 8;
#pragma unroll
      for (int cc = 0; cc < 6; ++cc) {
        const int c = w * 6 + cc;  // 24 chunks of 1 KB: 0..7 A, 8..23 B
        if (c < 8) {
          const int p = c >> 2, co = c & 3;
          gll16(pa + p * 4096 + co * 512, &As[p * 2048 + co * 512]);
        } else {
          const int cb = c - 8;
          gll16(pb + cb * 512, &Bs[cb * 512]);
        }
      }
    }
    __syncthreads();
    K4_MFMA();
  }
  // ---- y-half: k in [D, 2D) ----
  for (int ks = 0; ks < 32; ++ks) {
    const int kbA = ks * 2;
    const int kbW = 64 + ks * 2;
    __syncthreads();
    {
      const _Float16* pb = w1P + (size_t)(nIdx * 128 + kbW) * 4096 + l * 8;
#pragma unroll
      for (int cc = 0; cc < 4; ++cc) {
        const int cb = w * 4 + cc;
        gll16(pb + cb * 512, &Bs[cb * 512]);
      }
    }
#pragma unroll
    for (int it = 0; it < 2; ++it) {
      const int idx = it * 256 + tid;
      const int row = idx >> 3, p = (idx >> 2) & 1, slot = idx & 3;
      const int gy = iy_s[row];
      const _Float16* src = fhiP +
          ((size_t)((gy >> 7) * 64 + kbA + p) * 128 + (gy & 127)) * 32 +
          ((slot ^ ((gy >> 1) & 3)) << 3);
      *(uint4*)&As[p * 2048 + row * 32 + ((slot ^ ((row >> 1) & 3)) << 3)] =
          *(const uint4*)src;
    }
    __syncthreads();
    K4_MFMA();
  }
#undef K4_MFMA

#pragma unroll
  for (int nf = 0; nf < 2; ++nf) {
    const int gcol = n0 + w * 32 + nf * 16 + fr;
    const float bias = b1[gcol];
#pragma unroll
    for (int m = 0; m < 4; ++m)
#pragma unroll
      for (int reg = 0; reg < 4; ++reg) {
        const int grow = r0 + m * 16 + fg * 4 + reg;
        hout[(size_t)grow * H + gcol] = (_Float16)(acc[m][nf][reg] + bias);
      }
  }
}

// ---------------- K5: m = h @ w2 + b2 via f16 MFMA (bf16 out) ----------------
__global__ __launch_bounds__(256, 2) void k5_m(const _Float16* __restrict__ hbuf,
                                               const _Float16* __restrict__ w2T,
                                               const float* __restrict__ b2,
                                               unsigned short* __restrict__ mbuf) {
  __shared__ __align__(16) _Float16 As[128 * LDH], Bs[128 * LDH];
  const int tid = threadIdx.x;
  const int bid = blockIdx.x;
  const int b = (bid & 7) * 128 + (bid >> 3);  // XCD chunk swizzle (1024 = 8*128)
  const int n0 = (b & 15) * 128, r0 = (b >> 4) * 128;
  const int l = tid & 63, w = tid >> 6;
  const int wr = w >> 1, wc = w & 1, fr = l & 15, fg = l >> 4;
  f32x4 acc[4][4] = {};

  for (int k0 = 0; k0 < H; k0 += 32) {
    __syncthreads();
#pragma unroll
    for (int it = 0; it < 2; ++it) {
      const int c = it * 256 + tid;
      const int row = c >> 2, xc = c & 3;
      const int la = row * LDH + xc * 8;
      *(uint4*)&As[la] = *(const uint4*)(hbuf + (size_t)(r0 + row) * H + k0 + xc * 8);
      *(uint4*)&Bs[la] = *(const uint4*)(w2T + (size_t)(n0 + row) * H + k0 + xc * 8);
    }
    __syncthreads();
    f16x8 a[4], bb[4];
#pragma unroll
    for (int m = 0; m < 4; ++m) a[m] = *(const f16x8*)&As[(wr * 64 + m * 16 + fr) * LDH + fg * 8];
#pragma unroll
    for (int n = 0; n < 4; ++n) bb[n] = *(const f16x8*)&Bs[(wc * 64 + n * 16 + fr) * LDH + fg * 8];
#pragma unroll
    for (int m = 0; m < 4; ++m)
#pragma unroll
      for (int n = 0; n < 4; ++n)
        acc[m][n] = __builtin_amdgcn_mfma_f32_16x16x32_f16(a[m], bb[n], acc[m][n], 0, 0, 0);
  }
#pragma unroll
  for (int n = 0; n < 4; ++n) {
    const int gcol = n0 + wc * 64 + n * 16 + fr;
    const float bias = b2[gcol];
#pragma unroll
    for (int m = 0; m < 4; ++m)
#pragma unroll
      for (int reg = 0; reg < 4; ++reg) {
        const int grow = r0 + wr * 64 + m * 16 + fg * 4 + reg;
        mbuf[(size_t)grow * D + gcol] = f2bf(acc[m][n][reg] + bias);
      }
  }
}

// ---------------- K6: fused gates + 4 logit GEMMs, dbuf DMA-B, gate/MFMA overlap
__global__ __launch_bounds__(256, 2) void k6_logits(
    const float* __restrict__ feats, const unsigned short* __restrict__ mbuf,
    const int* __restrict__ iy, const _Float16* __restrict__ wfcP,
    const float* __restrict__ bfc, float* __restrict__ out) {
  __shared__ __align__(16) _Float16 As[2][64 * 64];   // 16 KB: gated A, dbuf
  __shared__ __align__(16) _Float16 Bs[2][14336];     // 56 KB: wfcP chunk, dbuf
  __shared__ int iy_s[16];
  const int tid = threadIdx.x;
  const int r0 = blockIdx.x * 16;
  const int l = tid & 63, v = tid >> 6;  // wave = variant
  const int fr = l & 15, fg = l >> 4;
  if (tid < 16) iy_s[tid] = iy[r0 + tid];
  __syncthreads();
  const int rr = tid >> 4;           // base row 0..15
  const int kq = (tid & 15) << 2;    // k offset within K64 chunk
  const int rg = r0 + rr;
  const float* xptr = feats + (size_t)(rg & (N - 1)) * D;
  const float* yptr = feats + (size_t)iy_s[rr] * D;
  const unsigned short* mptr = mbuf + (size_t)rg * D;
  const int wsw = ((rr >> 1) & 3) | ((rr & 1) << 2);               // write perm (3-bit)
  const int soff = ((((kq >> 3) ^ wsw)) << 3) + (kq & 7);
  const int rsw = (((fr >> 1) & 3) | ((fr & 1) << 2)) << 3;        // read perm << 3

  f32x4 acc[14] = {};

#define K6_GATES(buf, xv, yv, mv)                                     \
  do {                                                                \
    const float xs_[4] = {xv.x, xv.y, xv.z, xv.w};                    \
    const float ys_[4] = {yv.x, yv.y, yv.z, yv.w};                    \
    const unsigned short ms_[4] = {mv.x, mv.y, mv.z, mv.w};           \
    f16x4 a0, a1, a2, a3;                                             \
    _Pragma("unroll") for (int j = 0; j < 4; ++j) {                   \
      const float x = xs_[j], y = ys_[j], m = bf2f(ms_[j]);           \
      const float gx = sigm(m * x), gy = sigm(m * y);                 \
      a0[j] = (_Float16)(x * (1.0f + gx));                            \
      a1[j] = (_Float16)(x * (1.0f + gy));                            \
      a2[j] = (_Float16)(y * (1.0f + gy));                            \
      a3[j] = (_Float16)(y * (1.0f + gx));                            \
    }                                                                 \
    *(f16x4*)&As[buf][(rr)*64 + soff] = a0;                           \
    *(f16x4*)&As[buf][(16 + rr) * 64 + soff] = a1;                    \
    *(f16x4*)&As[buf][(32 + rr) * 64 + soff] = a2;                    \
    *(f16x4*)&As[buf][(48 + rr) * 64 + soff] = a3;                    \
  } while (0)

#define K6_STAGEB(k0n, buf)                                           \
  do {                                                                \
    const _Float16* src_ = wfcP + (size_t)((k0n) >> 5) * 7168;        \
    _Pragma("unroll") for (int c = 0; c < 7; ++c)                     \
      gll16(src_ + (c * 256 + tid) * 8, &Bs[buf][(c * 256 + tid) * 8]); \
  } while (0)

  // prologue: chunk 0 gates + B stage
  {
    float4 xv = *(const float4*)(xptr + kq);
    float4 yv = *(const float4*)(yptr + kq);
    ushort4 mv = *(const ushort4*)(mptr + kq);
    K6_STAGEB(0, 0);
    K6_GATES(0, xv, yv, mv);
  }

  for (int k0 = 0; k0 < D; k0 += 64) {
    const int cur = (k0 >> 6) & 1;
    __syncthreads();  // As[cur]/Bs[cur] ready (DMA drained, gate writes visible)
    float4 xv, yv; ushort4 mv;
    const bool more = (k0 + 64 < D);
    if (more) {  // issue next chunk's loads + DMA now; hide under MFMA phase
      xv = *(const float4*)(xptr + k0 + 64 + kq);
      yv = *(const float4*)(yptr + k0 + 64 + kq);
      mv = *(const ushort4*)(mptr + k0 + 64 + kq);
      K6_STAGEB(k0 + 64, cur ^ 1);
    }
#pragma unroll
    for (int ksl = 0; ksl < 2; ++ksl) {
      const f16x8 af =
          *(const f16x8*)&As[cur][(v * 16 + fr) * 64 + ((((ksl * 4 + fg) << 3)) ^ rsw)];
      const _Float16* bp = &Bs[cur][(size_t)ksl * 7168 + (size_t)l * 8];
#pragma unroll
      for (int nf = 0; nf < 14; ++nf) {
        const f16x8 bf = *(const f16x8*)(bp + nf * 512);
        acc[nf] = __builtin_amdgcn_mfma_f32_16x16x32_f16(af, bf, acc[nf], 0, 0, 0);
      }
    }
    if (more) K6_GATES(cur ^ 1, xv, yv, mv);  // VALU overlaps MFMA pipe
  }
#undef K6_GATES
#undef K6_STAGEB

  float* outv = out + (size_t)v * NR * C;
#pragma unroll
  for (int nf = 0; nf < 14; ++nf) {
    const int col = nf * 16 + fr;
    if (col < C) {
      const float bias = bfc[col];
#pragma unroll
      for (int reg = 0; reg < 4; ++reg) {
        const int row = r0 + fg * 4 + reg;
        outv[(size_t)row * C + col] = sigm(acc[nf][reg] + bias);
      }
    }
  }
}

extern "C" void kernel_launch(void* const* d_in, const int* in_sizes, int n_in,
                              void* d_out, int out_size, void* d_ws, size_t ws_size,
                              hipStream_t stream) {
  const float* feats = (const float*)d_in[0];
  const int*   tgt   = (const int*)d_in[1];
  const float* w1    = (const float*)d_in[2];
  const float* b1    = (const float*)d_in[3];
  const float* w2    = (const float*)d_in[4];
  const float* b2    = (const float*)d_in[5];
  const float* wfc   = (const float*)d_in[6];
  const float* bfc   = (const float*)d_in[7];
  float* out = (float*)d_out;

  char* ws = (char*)d_ws;
  float* sq = (float*)(ws);                       // 16 KB
  u64*   bi = (u64*)(ws + 16384);                 // 32 KB
  u64*   be = (u64*)(ws + 49152);                 // 32 KB
  int*   iy = (int*)(ws + 81920);                 // 32 KB
  _Float16* fhiP = (_Float16*)(ws + 131072);                 // 16 MB packed
  _Float16* floP = (_Float16*)(ws + 131072 + 16777216);      // 16 MB packed
  // mbuf (32 MB bf16) aliases fhiP+floP — both dead after k4 (k5 writes, k6 reads)
  unsigned short* mbuf = (unsigned short*)(ws + 131072);
  _Float16* w1P = (_Float16*)(ws + 33685504);                // 4 MB packed panels
  _Float16* w2T = (_Float16*)(ws + 37879808);                // 2 MB
  _Float16* hbuf = (_Float16*)(ws + 39976960);               // 8 MB
  _Float16* wfcP = (_Float16*)(ws + 48365568);               // 0.9 MB

  float* lab1 = out + (size_t)4 * NR * C;
  float* lab2 = lab1 + NR;

  kc_pack_k1<<<N, 256, 0, stream>>>(feats, fhiP, floP, sq, bi, be);
  kc_packW<<<dim3(128, 4), 256, 0, stream>>>(w1, w1P, 512, 128);
  kc_T<<<dim3(2048 / 32, 512 / 32), dim3(32, 8), 0, stream>>>(w2, w2T, 512, 2048);
  kc_wfc<<<dim3(64, 14), 64, 0, stream>>>(wfc, wfcP);
  k2_dist<<<528, 256, 0, stream>>>(fhiP, floP, tgt, sq, bi, be);
  k3_prep<<<NR / 256, 256, 0, stream>>>(tgt, bi, be, iy, lab1, lab2);
  k4_h<<<512, 256, 0, stream>>>(fhiP, w1P, b1, iy, hbuf);
  k5_m<<<1024, 256, 0, stream>>>(hbuf, w2T, b2, mbuf);
  k6_logits<<<NR / 16, 256, 0, stream>>>(feats, mbuf, iy, wfcP, bfc, out);
}